// Round 2
// baseline (226.676 us; speedup 1.0000x reference)
//
#include <hip/hip_runtime.h>

// DepthToSpace: in [8, 64, 256, 256] f32 -> out [8, 4, 1024, 1024] f32
// out[b, s, h*4+r, w*4+c] = in[b, s*16 + r*4 + c, h, w]
//
// One block per (b, s, h) slab:
//   load 16 channels x 256 floats (16 KB) via coalesced float4 -> LDS
//   each thread t gathers out float4 (ww=4t) of rows hh=4h+r from 4 LDS rows
//   store contiguous float4 (1 KiB/wave).
// All global traffic is dwordx4 both directions; LDS reads are bank-conflict
// free (addr % 32 == t % 32, 2 lanes/bank which is free on gfx950).

#define CH_STRIDE 65536  // H*W floats

__global__ __launch_bounds__(256) void DepthToSpace_8486855377460_kernel(
    const float* __restrict__ in, float* __restrict__ out) {
    __shared__ float lds[16 * 256];  // 16 KB: [channel within group][w]

    int t = threadIdx.x;          // 0..255
    int idx = blockIdx.x;         // ((b*4)+s)*256 + h
    int h = idx & 255;
    int s = (idx >> 8) & 3;
    int b = idx >> 10;

    const float* src = in + ((size_t)(b * 64 + s * 16)) * CH_STRIDE + h * 256;

    // Load phase: 1024 float4s across 256 threads (4 each).
    // j = k*256 + t; ch = j/64 (wave-uniform), w4 = j%64 (=lane) -> contiguous 1 KiB/wave.
#pragma unroll
    for (int k = 0; k < 4; ++k) {
        int j = k * 256 + t;
        int ch = j >> 6;
        int w4 = j & 63;
        float4 v = *(const float4*)(src + ch * CH_STRIDE + w4 * 4);
        *(float4*)(&lds[ch * 256 + w4 * 4]) = v;
    }

    __syncthreads();

    // Store phase: output rows hh = 4h + r, r=0..3. Thread t -> float4 at ww=4t.
    float* dst = out + (((size_t)(b * 4 + s) * 1024) + h * 4) * 1024;
#pragma unroll
    for (int r = 0; r < 4; ++r) {
        float4 v;
        v.x = lds[(4 * r + 0) * 256 + t];
        v.y = lds[(4 * r + 1) * 256 + t];
        v.z = lds[(4 * r + 2) * 256 + t];
        v.w = lds[(4 * r + 3) * 256 + t];
        ((float4*)(dst + r * 1024))[t] = v;
    }
}

extern "C" void kernel_launch(void* const* d_in, const int* in_sizes, int n_in,
                              void* d_out, int out_size, void* d_ws, size_t ws_size,
                              hipStream_t stream) {
    const float* x = (const float*)d_in[0];
    float* out = (float*)d_out;
    dim3 block(256);
    dim3 grid(8 * 4 * 256);  // one block per (b, s, h) = 8192 blocks
    DepthToSpace_8486855377460_kernel<<<grid, block, 0, stream>>>(x, out);
}